// Round 1
// baseline (908.688 us; speedup 1.0000x reference)
//
#include <hip/hip_runtime.h>
#include <math.h>

// Problem constants (B=4, T=512, H=2048, V=32000)
#define BATCH 4
#define TSEQ 512
#define MTOK 2048          // B*T
#define HDIM 2048
#define VOCAB 32000
#define NCHUNK 500         // VOCAB / 64
#define IGNORE_INDEX (-100)
#define BETA 0.1f

// W is quantized as fp8(W*16) and de-scaled in-MFMA via uniform MX scale 2^-4
#define WSCALE 16.0f
#define SCALE_ONE  0x7F7F7F7F   // E8M0 127 = 2^0  in all 4 bytes
#define SCALE_W    0x7B7B7B7B   // E8M0 123 = 2^-4 in all 4 bytes

// convert geometry: 8192 float4s per block (256 thr x 32 iters)
#define CVT_PER_BLOCK 8192
#define WCVT_BLK (VOCAB * HDIM / 4 / CVT_PER_BLOCK)   // 2000 blocks per W
#define XCVT_BLK (MTOK * HDIM / 4 / CVT_PER_BLOCK)    // 128 blocks per x

typedef __attribute__((ext_vector_type(4))) float floatx4;
typedef __attribute__((ext_vector_type(4))) int   intx4;
typedef __attribute__((ext_vector_type(8))) int   intx8;

// ---------------------------------------------------------------- utilities
__device__ __forceinline__ void async_copy16b(const unsigned char* g, unsigned char* l) {
    __builtin_amdgcn_global_load_lds(
        (const __attribute__((address_space(1))) void*)g,
        (__attribute__((address_space(3))) void*)l, 16, 0, 0);
}

// ------------------------------------------------------ fp32 -> fp8 e4m3
__device__ __forceinline__ void cvtq_run(const float* __restrict__ src,
                                         unsigned int* __restrict__ dst,
                                         int relblk, float scale) {
    size_t base = (size_t)relblk * CVT_PER_BLOCK + threadIdx.x;
    const floatx4* s4 = (const floatx4*)src;
#pragma unroll
    for (int k = 0; k < 32; ++k) {
        floatx4 a = s4[base + k * 256];
        int lo  = __builtin_amdgcn_cvt_pk_fp8_f32(a[0] * scale, a[1] * scale, 0,  false);
        int all = __builtin_amdgcn_cvt_pk_fp8_f32(a[2] * scale, a[3] * scale, lo, true);
        dst[base + k * 256] = (unsigned int)all;
    }
}

// --------------------------------------------- fp32 -> fp8, all 4 tensors
__global__ __launch_bounds__(256) void cvtq_all_kernel(
        const float* __restrict__ s0, const float* __restrict__ s1,
        const float* __restrict__ s2, const float* __restrict__ s3,
        unsigned int* __restrict__ d0, unsigned int* __restrict__ d1,
        unsigned int* __restrict__ d2, unsigned int* __restrict__ d3) {
    int b = blockIdx.x;
    if (b < WCVT_BLK)                     cvtq_run(s0, d0, b, WSCALE);
    else if (b < 2 * WCVT_BLK)            cvtq_run(s1, d1, b - WCVT_BLK, WSCALE);
    else if (b < 2 * WCVT_BLK + XCVT_BLK) cvtq_run(s2, d2, b - 2 * WCVT_BLK, 1.0f);
    else                                  cvtq_run(s3, d3, b - 2 * WCVT_BLK - XCVT_BLK, 1.0f);
}

// ------------------------------------------------ fp32 -> fp8, one tensor
__global__ __launch_bounds__(256) void cvtq_one_kernel(
        const float* __restrict__ src, unsigned int* __restrict__ dst, float scale) {
    cvtq_run(src, dst, blockIdx.x, scale);
}

// =====================================================================
// MX-FP8 GEMM + fused LSE — 256x256 tile, 8-wave, 4-phase/K-tile schedule
// (T2 swizzle + T3 phase split + T4 counted vmcnt + T5 setprio).
//
// Geometry: BM=BN=256, BK=128 B (=128 fp8 elems, one 16x16x128 MFMA K).
// 8 waves as 2(M) x 4(N); per-wave output 128x64 = acc[8][4].
// LDS: 2 slots x (A 32KB + B 32KB) = 128 KB, 1 block/CU.
//
// Per K-tile u (slot u&1), 4 phases, each = [ds_read quadrant frags;
// stage ONE half-tile (2 x global_load_lds); s_barrier; lgkmcnt(0);
// setprio(1); 8 MFMA; setprio(0); (phase3: vmcnt(4)); s_barrier]:
//   phase0: C(m-lo, n0..1)  reads afl+bfa   stages (u+1) A-lo -> other slot
//   phase1: C(m-lo, n2..3)  reads bfb       stages (u+1) A-hi -> other slot
//   phase2: C(m-hi, n2..3)  reads afh       stages (u+2) B-lo -> THIS slot
//   phase3: C(m-hi, n0..1)  (reuse bfa)     stages (u+2) B-hi -> THIS slot
// Hazards: A halves of a slot are last read in phase2 of their tile, B
// halves in phase1; each half is overwritten >=1 full phase (barrier pair)
// after its last read. vmcnt(4) at phase3 keeps exactly the 2 youngest
// half-tiles (4 loads) in flight and retires tile u+1 before its phase0.
// Tiles 16/17 are staged with wrapped K (data unused) so the vmcnt
// arithmetic stays uniform through the tail.
//
// LDS rows are 128 B = 8 x 16B chunks; global chunk g of row r sits at
// position g^(r&7) (staging permutes the SOURCE address; dest stays
// wave-uniform base + lane*16 as global_load_lds requires).
// =====================================================================
#define BKF 128
#define BM  256
#define BN  256

__device__ __forceinline__ intx8 frag_ld(const unsigned char* base, int row, int q) {
    const int p0 = (2 * q) ^ (row & 7);
    const intx4 lo = *(const intx4*)(base + row * BKF + p0 * 16);
    const intx4 hi = *(const intx4*)(base + row * BKF + (p0 ^ 1) * 16);
    intx8 v;
    v[0] = lo[0]; v[1] = lo[1]; v[2] = lo[2]; v[3] = lo[3];
    v[4] = hi[0]; v[5] = hi[1]; v[6] = hi[2]; v[7] = hi[3];
    return v;
}

#define MFMA8(ACC_I, ACC_J, AF, BF)                                           \
    _Pragma("unroll")                                                         \
    for (int i = 0; i < 4; ++i) {                                             \
        _Pragma("unroll")                                                     \
        for (int j = 0; j < 2; ++j)                                           \
            acc[(ACC_I) + i][(ACC_J) + j] =                                   \
                __builtin_amdgcn_mfma_scale_f32_16x16x128_f8f6f4(             \
                    AF[i], BF[j], acc[(ACC_I) + i][(ACC_J) + j],              \
                    0, 0, 0, SCALE_ONE, 0, SCALE_W);                          \
    }

// stage one 128-row half (hh=0 lo, hh=1 hi) of a tile: 2 loads/thread
#define STG(gp, ls, hh, kk) do {                                                          \
    async_copy16b((gp) + (size_t)(hh) * 128 * HDIM + (kk),            (ls) + (hh) * 16384 + e0); \
    async_copy16b((gp) + (size_t)(hh) * 128 * HDIM + 64 * HDIM + (kk),(ls) + (hh) * 16384 + 8192 + e0); \
} while (0)

__global__ __launch_bounds__(512, 2) void gemm_lse_fp8_kernel(
        const unsigned char* __restrict__ Xq0,
        const unsigned char* __restrict__ Xq1,
        const unsigned char* __restrict__ Wq0,
        const unsigned char* __restrict__ Wq1,
        const int* __restrict__ y,               // M labels
        float* __restrict__ pmax,                // [slot][M][NCHUNK]
        float* __restrict__ psum,                // [slot][M][NCHUNK]
        float* __restrict__ tlog,                // [slot][M]
        int slot_base)
{
    __shared__ __align__(16) unsigned char sAB[2][2][BM * BKF];   // 128 KB

    const int slot = slot_base + blockIdx.z;
    const unsigned char* __restrict__ Xq = slot ? Xq1 : Xq0;
    const unsigned char* __restrict__ Wq = slot ? Wq1 : Wq0;

    const int tid  = threadIdx.x;
    const int m0   = blockIdx.x * BM;
    const int v0   = blockIdx.y * BN;
    const int w    = tid >> 6;
    const int lane = tid & 63;
    const int wm   = w >> 2;        // 0..1 token half (128 rows)
    const int wn   = w & 3;         // 0..3 vocab quarter (64 rows)
    const int c    = lane & 15;
    const int q    = lane >> 4;

    // staging geometry: 512 thr x 16 B = 64 rows per issue
    const int e0    = tid * 16;                         // 0..8191
    const int srow  = e0 >> 7;                          // 0..63
    const int colsw = (((e0 >> 4) & 7) ^ (srow & 7)) * 16;  // swizzled src col
    const unsigned char* aP = Xq + (size_t)(m0 + srow) * HDIM + colsw;
    const unsigned char* bP = Wq + (size_t)(v0 + srow) * HDIM + colsw;

    unsigned char* const L0A = &sAB[0][0][0];
    unsigned char* const L0B = &sAB[0][1][0];
    unsigned char* const L1B = &sAB[1][1][0];

    // prologue: mirror steady-state issue order
    STG(bP, L0B, 0, 0);          // tile0 B-lo
    STG(bP, L0B, 1, 0);          // tile0 B-hi
    STG(aP, L0A, 0, 0);          // tile0 A-lo
    STG(aP, L0A, 1, 0);          // tile0 A-hi
    STG(bP, L1B, 0, BKF);        // tile1 B-lo
    STG(bP, L1B, 1, BKF);        // tile1 B-hi

    floatx4 acc[8][4] = {};
    const int arow = wm * 128 + c;
    const int brow = wn * 64 + c;

    asm volatile("s_waitcnt vmcnt(4)" ::: "memory");   // tile0 fully landed
    __builtin_amdgcn_s_barrier();

    for (int u = 0; u < HDIM / BKF; ++u) {             // 16 K-tiles
        unsigned char* const A  = &sAB[u & 1][0][0];
        unsigned char* const B  = &sAB[u & 1][1][0];
        unsigned char* const NA = &sAB[(u + 1) & 1][0][0];
        const int kk1 = ((u + 1) & 15) * BKF;
        const int kk2 = ((u + 2) & 15) * BKF;

        intx8 afl[4], afh[4], bfa[2], bfb[2];

        // ---- phase 0: (m-lo, n0..1) ----
#pragma unroll
        for (int i = 0; i < 4; ++i) afl[i] = frag_ld(A, arow + i * 16, q);
#pragma unroll
        for (int j = 0; j < 2; ++j) bfa[j] = frag_ld(B, brow + j * 16, q);
        STG(aP, NA, 0, kk1);                           // (u+1) A-lo
        __builtin_amdgcn_s_barrier();
        asm volatile("s_waitcnt lgkmcnt(0)" ::: "memory");
        __builtin_amdgcn_s_setprio(1);
        MFMA8(0, 0, afl, bfa);
        __builtin_amdgcn_s_setprio(0);
        __builtin_amdgcn_s_barrier();

        // ---- phase 1: (m-lo, n2..3) ----
#pragma unroll
        for (int j = 0; j < 2; ++j) bfb[j] = frag_ld(B, brow + 32 + j * 16, q);
        STG(aP, NA, 1, kk1);                           // (u+1) A-hi
        __builtin_amdgcn_s_barrier();
        asm volatile("s_waitcnt lgkmcnt(0)" ::: "memory");
        __builtin_amdgcn_s_setprio(1);
        MFMA8(0, 2, afl, bfb);
        __builtin_amdgcn_s_setprio(0);
        __builtin_amdgcn_s_barrier();

        // ---- phase 2: (m-hi, n2..3) ----
#pragma unroll
        for (int i = 0; i < 4; ++i) afh[i] = frag_ld(A, arow + 64 + i * 16, q);
        STG(bP, B, 0, kk2);                            // (u+2) B-lo (same slot)
        __builtin_amdgcn_s_barrier();
        asm volatile("s_waitcnt lgkmcnt(0)" ::: "memory");
        __builtin_amdgcn_s_setprio(1);
        MFMA8(4, 2, afh, bfb);
        __builtin_amdgcn_s_setprio(0);
        __builtin_amdgcn_s_barrier();

        // ---- phase 3: (m-hi, n0..1) ----
        STG(bP, B, 1, kk2);                            // (u+2) B-hi (same slot)
        __builtin_amdgcn_s_barrier();
        __builtin_amdgcn_s_setprio(1);
        MFMA8(4, 0, afh, bfa);
        __builtin_amdgcn_s_setprio(0);
        asm volatile("s_waitcnt vmcnt(4)" ::: "memory");  // tile u+1 landed
        __builtin_amdgcn_s_barrier();
    }

    // ------------- epilogue: fused LSE over this block's 64-col chunks
    // C/D layout: col = lane&15 (vocab), row = q*4+r (token)
    const int chunk = blockIdx.y * 4 + wn;
#pragma unroll
    for (int i = 0; i < 8; ++i) {
        float mx[4], sm[4];
#pragma unroll
        for (int r = 0; r < 4; ++r) {
            float m4 = acc[i][0][r];
            m4 = fmaxf(m4, acc[i][1][r]);
            m4 = fmaxf(m4, acc[i][2][r]);
            m4 = fmaxf(m4, acc[i][3][r]);
            mx[r] = m4;
        }
#pragma unroll
        for (int d = 1; d < 16; d <<= 1)
#pragma unroll
            for (int r = 0; r < 4; ++r)
                mx[r] = fmaxf(mx[r], __shfl_xor(mx[r], d, 64));
#pragma unroll
        for (int r = 0; r < 4; ++r) {
            float s = 0.f;
#pragma unroll
            for (int j = 0; j < 4; ++j) s += expf(acc[i][j][r] - mx[r]);
            sm[r] = s;
        }
#pragma unroll
        for (int d = 1; d < 16; d <<= 1)
#pragma unroll
            for (int r = 0; r < 4; ++r)
                sm[r] += __shfl_xor(sm[r], d, 64);

        const int tokenBase = m0 + wm * 128 + i * 16 + q * 4;
        if (c == 0) {
#pragma unroll
            for (int r = 0; r < 4; ++r) {
                pmax[(size_t)(slot * MTOK + tokenBase + r) * NCHUNK + chunk] = mx[r];
                psum[(size_t)(slot * MTOK + tokenBase + r) * NCHUNK + chunk] = sm[r];
            }
        }
        // target-logit capture — LITERAL j index only (runtime index into acc
        // demotes the accumulator to scratch)
#pragma unroll
        for (int r = 0; r < 4; ++r) {
            int lab = y[tokenBase + r];
            int rel = lab - (v0 + wn * 64);
            if (rel >= 0 && rel < 64 && (rel & 15) == c) {
#pragma unroll
                for (int j = 0; j < 4; ++j)
                    if ((rel >> 4) == j)
                        tlog[(size_t)slot * MTOK + tokenBase + r] = acc[i][j][r];
            }
        }
    }
}

// --------------------------------------------- per-token logp (wave/token)
__global__ __launch_bounds__(256) void finalize_kernel(
        const int* __restrict__ y,
        const float* __restrict__ pmax,
        const float* __restrict__ psum,
        const float* __restrict__ tlog,
        float* __restrict__ tokll, int slot_base) {
    const int wv    = threadIdx.x >> 6;
    const int lane  = threadIdx.x & 63;
    const int token = blockIdx.x * 4 + wv;
    const int slot  = slot_base + blockIdx.y;

    const float* pm = &pmax[(size_t)(slot * MTOK + token) * NCHUNK];
    const float* ps = &psum[(size_t)(slot * MTOK + token) * NCHUNK];
    float m = -3.4e38f, s = 0.f;
    for (int c2 = lane; c2 < NCHUNK; c2 += 64) {
        float cm = pm[c2];
        float cs = ps[c2];
        if (cm > m) { s = s * expf(m - cm) + cs; m = cm; }
        else        { s += cs * expf(cm - m); }
    }
#pragma unroll
    for (int d = 1; d < 64; d <<= 1) {
        float om = __shfl_xor(m, d, 64);
        float os = __shfl_xor(s, d, 64);
        if (om > m) { s = s * expf(m - om) + os; m = om; }
        else        { s += os * expf(om - m); }
    }
    if (lane == 0) {
        int lab = y[token];
        float lse = m + logf(s);
        tokll[(size_t)slot * MTOK + token] =
            (lab == IGNORE_INDEX) ? 0.f : (tlog[(size_t)slot * MTOK + token] - lse);
    }
}

// ---------------------------------- fused seq-average + KTO loss, 1 block
__global__ __launch_bounds__(256) void tail_kernel(
        const int* __restrict__ y,
        const float* __restrict__ tokll,
        const int* __restrict__ pref,
        float* __restrict__ out) {
    __shared__ float rs[256];
    __shared__ float rc[256];
    __shared__ float seqavg[8];
    const int tid = threadIdx.x;
    for (int sb = 0; sb < 8; ++sb) {
        const int slot = sb >> 2;
        const int b    = sb & 3;
        float lsum = 0.f, lcnt = 0.f;
        for (int t = tid; t < TSEQ; t += 256) {
            int token = b * TSEQ + t;
            lsum += tokll[(size_t)slot * MTOK + token];
            lcnt += (y[token] != IGNORE_INDEX) ? 1.f : 0.f;
        }
        rs[tid] = lsum; rc[tid] = lcnt;
        __syncthreads();
        for (int s2 = 128; s2 > 0; s2 >>= 1) {
            if (tid < s2) { rs[tid] += rs[tid + s2]; rc[tid] += rc[tid + s2]; }
            __syncthreads();
        }
        if (tid == 0) seqavg[sb] = rs[0] / rc[0];
        __syncthreads();
    }
    if (tid == 0) {
        float acc = 0.f;
        for (int b = 0; b < BATCH; ++b) {
            float lr   = seqavg[b] - seqavg[BATCH + b];
            float mult = pref[b] ? 1.f : -1.f;
            float z    = BETA * lr * mult;
            float sig  = 1.f / (1.f + expf(-z));
            acc += 1.f - sig;
        }
        out[0] = acc * (1.f / (float)BATCH);
    }
}

// ---------------------------------------------------------------- launcher
extern "C" void kernel_launch(void* const* d_in, const int* in_sizes, int n_in,
                              void* d_out, int out_size, void* d_ws, size_t ws_size,
                              hipStream_t stream) {
    const float* x      = (const float*)d_in[0];
    const float* ref_x  = (const float*)d_in[1];
    const int*   y      = (const int*)d_in[2];
    const int*   pref   = (const int*)d_in[3];
    const float* W      = (const float*)d_in[4];
    const float* ref_W  = (const float*)d_in[5];
    float* out = (float*)d_out;
    char*  ws  = (char*)d_ws;

    const size_t WQSZ = (size_t)VOCAB * HDIM;      // 65,536,000 B fp8
    const size_t XQSZ = (size_t)MTOK * HDIM;       //  4,194,304 B fp8
    const size_t PSZ  = (size_t)2 * MTOK * NCHUNK * 4;  // dual-slot pmax/psum

    const size_t need_dual = 2*WQSZ + 2*XQSZ + 2*PSZ + (size_t)4*MTOK*4 + 4096;

    if (ws_size >= need_dual) {
        unsigned char* wq0 = (unsigned char*)(ws);
        unsigned char* wq1 = (unsigned char*)(ws + WQSZ);
        unsigned char* xq0 = (unsigned char*)(ws + 2*WQSZ);
        unsigned char* xq1 = (unsigned char*)(ws + 2*WQSZ + XQSZ);
        float* pmax  = (float*)(ws + 2*WQSZ + 2*XQSZ);
        float* psum  = (float*)(ws + 2*WQSZ + 2*XQSZ + PSZ);
        float* tlog  = (float*)(ws + 2*WQSZ + 2*XQSZ + 2*PSZ);
        float* tokll = (float*)(ws + 2*WQSZ + 2*XQSZ + 2*PSZ + (size_t)2*MTOK*4);

        cvtq_all_kernel<<<2*WCVT_BLK + 2*XCVT_BLK, 256, 0, stream>>>(
            W, ref_W, x, ref_x,
            (unsigned int*)wq0, (unsigned int*)wq1,
            (unsigned int*)xq0, (unsigned int*)xq1);
        gemm_lse_fp8_kernel<<<dim3(MTOK/BM, VOCAB/BN, 2), 512, 0, stream>>>(
            xq0, xq1, wq0, wq1, y, pmax, psum, tlog, 0);
        finalize_kernel<<<dim3(MTOK/4, 2), 256, 0, stream>>>(
            y, pmax, psum, tlog, tokll, 0);
        tail_kernel<<<1, 256, 0, stream>>>(y, tokll, pref, out);
    } else {
        // serial fallback: single W/X buffer reused per model
        unsigned char* wq = (unsigned char*)(ws);
        unsigned char* xq = (unsigned char*)(ws + WQSZ);
        float* pmax  = (float*)(ws + WQSZ + XQSZ);
        float* psum  = (float*)(ws + WQSZ + XQSZ + PSZ);
        float* tlog  = (float*)(ws + WQSZ + XQSZ + 2*PSZ);
        float* tokll = (float*)(ws + WQSZ + XQSZ + 2*PSZ + (size_t)2*MTOK*4);

        for (int model = 0; model < 2; ++model) {
            const float* xin = model ? ref_x : x;
            const float* win = model ? ref_W : W;
            cvtq_one_kernel<<<WCVT_BLK, 256, 0, stream>>>(win, (unsigned int*)wq, WSCALE);
            cvtq_one_kernel<<<XCVT_BLK, 256, 0, stream>>>(xin, (unsigned int*)xq, 1.0f);
            gemm_lse_fp8_kernel<<<dim3(MTOK/BM, VOCAB/BN, 1), 512, 0, stream>>>(
                xq, xq, wq, wq, y, pmax, psum, tlog, model);
            finalize_kernel<<<dim3(MTOK/4, 1), 256, 0, stream>>>(
                y, pmax, psum, tlog, tokll, model);
        }
        tail_kernel<<<1, 256, 0, stream>>>(y, tokll, pref, out);
    }
}

// Round 4
// 906.490 us; speedup vs baseline: 1.0024x; 1.0024x over previous
//
#include <hip/hip_runtime.h>
#include <math.h>

// Problem constants (B=4, T=512, H=2048, V=32000)
#define BATCH 4
#define TSEQ 512
#define MTOK 2048          // B*T
#define HDIM 2048
#define VOCAB 32000
#define NCHUNK 500         // VOCAB / 64
#define IGNORE_INDEX (-100)
#define BETA 0.1f

// W is quantized as fp8(W*16) and de-scaled in-MFMA via uniform MX scale 2^-4
#define WSCALE 16.0f
#define SCALE_ONE  0x7F7F7F7F   // E8M0 127 = 2^0  in all 4 bytes
#define SCALE_W    0x7B7B7B7B   // E8M0 123 = 2^-4 in all 4 bytes

// convert geometry: 8192 float4s per block (256 thr x 32 iters)
#define CVT_PER_BLOCK 8192
#define WCVT_BLK (VOCAB * HDIM / 4 / CVT_PER_BLOCK)   // 2000 blocks per W
#define XCVT_BLK (MTOK * HDIM / 4 / CVT_PER_BLOCK)    // 128 blocks per x

typedef __attribute__((ext_vector_type(4))) float floatx4;
typedef __attribute__((ext_vector_type(4))) int   intx4;
typedef __attribute__((ext_vector_type(8))) int   intx8;

// ---------------------------------------------------------------- utilities
__device__ __forceinline__ void async_copy16b(const unsigned char* g, unsigned char* l) {
    __builtin_amdgcn_global_load_lds(
        (const __attribute__((address_space(1))) void*)g,
        (__attribute__((address_space(3))) void*)l, 16, 0, 0);
}

// ------------------------------------------------------ fp32 -> fp8 e4m3
__device__ __forceinline__ void cvtq_run(const float* __restrict__ src,
                                         unsigned int* __restrict__ dst,
                                         int relblk, float scale) {
    size_t base = (size_t)relblk * CVT_PER_BLOCK + threadIdx.x;
    const floatx4* s4 = (const floatx4*)src;
#pragma unroll
    for (int k = 0; k < 32; ++k) {
        floatx4 a = s4[base + k * 256];
        int lo  = __builtin_amdgcn_cvt_pk_fp8_f32(a[0] * scale, a[1] * scale, 0,  false);
        int all = __builtin_amdgcn_cvt_pk_fp8_f32(a[2] * scale, a[3] * scale, lo, true);
        dst[base + k * 256] = (unsigned int)all;
    }
}

// --------------------------------------------- fp32 -> fp8, all 4 tensors
__global__ __launch_bounds__(256) void cvtq_all_kernel(
        const float* __restrict__ s0, const float* __restrict__ s1,
        const float* __restrict__ s2, const float* __restrict__ s3,
        unsigned int* __restrict__ d0, unsigned int* __restrict__ d1,
        unsigned int* __restrict__ d2, unsigned int* __restrict__ d3) {
    int b = blockIdx.x;
    if (b < WCVT_BLK)                     cvtq_run(s0, d0, b, WSCALE);
    else if (b < 2 * WCVT_BLK)            cvtq_run(s1, d1, b - WCVT_BLK, WSCALE);
    else if (b < 2 * WCVT_BLK + XCVT_BLK) cvtq_run(s2, d2, b - 2 * WCVT_BLK, 1.0f);
    else                                  cvtq_run(s3, d3, b - 2 * WCVT_BLK - XCVT_BLK, 1.0f);
}

// ------------------------------------------------ fp32 -> fp8, one tensor
__global__ __launch_bounds__(256) void cvtq_one_kernel(
        const float* __restrict__ src, unsigned int* __restrict__ dst, float scale) {
    cvtq_run(src, dst, blockIdx.x, scale);
}

// =====================================================================
// MX-FP8 GEMM + fused LSE — 256x256 tile, 8-wave, 4-phase/K-tile schedule
// (T2 swizzle + T3 phase split + T4 counted vmcnt + T5 setprio)
// + 2-D XCD-aware tile swizzle.
//
// R1 diagnosis: FETCH_SIZE = 609 MB/model vs 70 MB compulsory. With
// gridDim.x == 8 and XCD == linear%8, XCD == blockIdx.x: the 8 M-blocks
// sharing each W panel land on 8 DIFFERENT XCDs, so every XCD streams
// the whole 64 MB W through its private L2 (8x512KB panels x 125 = 512MB
// of L2 fill == the measured FETCH). Staging throttles at ~4.5 B/cyc/CU.
//
// Fix: pad grid.y to 128 (24 dead blocks exit early; 1024 = 4 exact
// rounds) and give each XCD a 2-D chunk: x-half (4 M-tiles, 2 MB of X)
// x y-quarter (32 W panels). Within an XCD blocks sweep x fastest, so a
// W panel is reused by 4 consecutive blocks out of one L2, and the 4
// X tiles stay L2-resident. Per-XCD L2 fill drops ~8x for W.
// Mapping is bijective; early-exit is block-uniform and precedes any
// barrier, so sync structure is untouched from the verified R1 kernel.
// =====================================================================
#define BKF 128
#define BM  256
#define BN  256
#define VPANELS 125        // VOCAB / BN
#define GRIDY   128        // padded panel count (8 XCDs x 32)

__device__ __forceinline__ intx8 frag_ld(const unsigned char* base, int row, int q) {
    const int p0 = (2 * q) ^ (row & 7);
    const intx4 lo = *(const intx4*)(base + row * BKF + p0 * 16);
    const intx4 hi = *(const intx4*)(base + row * BKF + (p0 ^ 1) * 16);
    intx8 v;
    v[0] = lo[0]; v[1] = lo[1]; v[2] = lo[2]; v[3] = lo[3];
    v[4] = hi[0]; v[5] = hi[1]; v[6] = hi[2]; v[7] = hi[3];
    return v;
}

#define MFMA8(ACC_I, ACC_J, AF, BF)                                           \
    _Pragma("unroll")                                                         \
    for (int i = 0; i < 4; ++i) {                                             \
        _Pragma("unroll")                                                     \
        for (int j = 0; j < 2; ++j)                                           \
            acc[(ACC_I) + i][(ACC_J) + j] =                                   \
                __builtin_amdgcn_mfma_scale_f32_16x16x128_f8f6f4(             \
                    AF[i], BF[j], acc[(ACC_I) + i][(ACC_J) + j],              \
                    0, 0, 0, SCALE_ONE, 0, SCALE_W);                          \
    }

// stage one 128-row half (hh=0 lo, hh=1 hi) of a tile: 2 loads/thread
#define STG(gp, ls, hh, kk) do {                                                          \
    async_copy16b((gp) + (size_t)(hh) * 128 * HDIM + (kk),            (ls) + (hh) * 16384 + e0); \
    async_copy16b((gp) + (size_t)(hh) * 128 * HDIM + 64 * HDIM + (kk),(ls) + (hh) * 16384 + 8192 + e0); \
} while (0)

__global__ __launch_bounds__(512, 2) void gemm_lse_fp8_kernel(
        const unsigned char* __restrict__ Xq0,
        const unsigned char* __restrict__ Xq1,
        const unsigned char* __restrict__ Wq0,
        const unsigned char* __restrict__ Wq1,
        const int* __restrict__ y,               // M labels
        float* __restrict__ pmax,                // [slot][M][NCHUNK]
        float* __restrict__ psum,                // [slot][M][NCHUNK]
        float* __restrict__ tlog,                // [slot][M]
        int slot_base)
{
    // ---- 2-D XCD-aware tile swizzle (XCD = linear_block_id % 8) ----
    // xcd -> (kx = xcd&1, ky = xcd>>1): owns x in [kx*4, kx*4+4),
    //                                   y in [ky*32, ky*32+32).
    // Within the XCD: x fastest (W-panel reuse by 4 consecutive blocks).
    const int lin = blockIdx.x + (int)(gridDim.x) * blockIdx.y;   // gridDim.x == 8
    const int xcd = lin & 7;
    const int t   = lin >> 3;                  // 0..127
    const int bx  = (xcd & 1) * 4 + (t & 3);   // 0..7  (M tile)
    const int by  = (xcd >> 1) * 32 + (t >> 2);// 0..127 (V panel, padded)
    if (by >= VPANELS) return;                 // uniform early exit (pad blocks)

    __shared__ __align__(16) unsigned char sAB[2][2][BM * BKF];   // 128 KB

    const int slot = slot_base + blockIdx.z;
    const unsigned char* __restrict__ Xq = slot ? Xq1 : Xq0;
    const unsigned char* __restrict__ Wq = slot ? Wq1 : Wq0;

    const int tid  = threadIdx.x;
    const int m0   = bx * BM;
    const int v0   = by * BN;
    const int w    = tid >> 6;
    const int lane = tid & 63;
    const int wm   = w >> 2;        // 0..1 token half (128 rows)
    const int wn   = w & 3;         // 0..3 vocab quarter (64 rows)
    const int c    = lane & 15;
    const int q    = lane >> 4;

    // staging geometry: 512 thr x 16 B = 64 rows per issue
    const int e0    = tid * 16;                         // 0..8191
    const int srow  = e0 >> 7;                          // 0..63
    const int colsw = (((e0 >> 4) & 7) ^ (srow & 7)) * 16;  // swizzled src col
    const unsigned char* aP = Xq + (size_t)(m0 + srow) * HDIM + colsw;
    const unsigned char* bP = Wq + (size_t)(v0 + srow) * HDIM + colsw;

    unsigned char* const L0A = &sAB[0][0][0];
    unsigned char* const L0B = &sAB[0][1][0];
    unsigned char* const L1B = &sAB[1][1][0];

    // prologue: mirror steady-state issue order
    STG(bP, L0B, 0, 0);          // tile0 B-lo
    STG(bP, L0B, 1, 0);          // tile0 B-hi
    STG(aP, L0A, 0, 0);          // tile0 A-lo
    STG(aP, L0A, 1, 0);          // tile0 A-hi
    STG(bP, L1B, 0, BKF);        // tile1 B-lo
    STG(bP, L1B, 1, BKF);        // tile1 B-hi

    floatx4 acc[8][4] = {};
    const int arow = wm * 128 + c;
    const int brow = wn * 64 + c;

    asm volatile("s_waitcnt vmcnt(4)" ::: "memory");   // tile0 fully landed
    __builtin_amdgcn_s_barrier();

    for (int u = 0; u < HDIM / BKF; ++u) {             // 16 K-tiles
        unsigned char* const A  = &sAB[u & 1][0][0];
        unsigned char* const B  = &sAB[u & 1][1][0];
        unsigned char* const NA = &sAB[(u + 1) & 1][0][0];
        const int kk1 = ((u + 1) & 15) * BKF;
        const int kk2 = ((u + 2) & 15) * BKF;

        intx8 afl[4], afh[4], bfa[2], bfb[2];

        // ---- phase 0: (m-lo, n0..1) ----
#pragma unroll
        for (int i = 0; i < 4; ++i) afl[i] = frag_ld(A, arow + i * 16, q);
#pragma unroll
        for (int j = 0; j < 2; ++j) bfa[j] = frag_ld(B, brow + j * 16, q);
        STG(aP, NA, 0, kk1);                           // (u+1) A-lo
        __builtin_amdgcn_s_barrier();
        asm volatile("s_waitcnt lgkmcnt(0)" ::: "memory");
        __builtin_amdgcn_s_setprio(1);
        MFMA8(0, 0, afl, bfa);
        __builtin_amdgcn_s_setprio(0);
        __builtin_amdgcn_s_barrier();

        // ---- phase 1: (m-lo, n2..3) ----
#pragma unroll
        for (int j = 0; j < 2; ++j) bfb[j] = frag_ld(B, brow + 32 + j * 16, q);
        STG(aP, NA, 1, kk1);                           // (u+1) A-hi
        __builtin_amdgcn_s_barrier();
        asm volatile("s_waitcnt lgkmcnt(0)" ::: "memory");
        __builtin_amdgcn_s_setprio(1);
        MFMA8(0, 2, afl, bfb);
        __builtin_amdgcn_s_setprio(0);
        __builtin_amdgcn_s_barrier();

        // ---- phase 2: (m-hi, n2..3) ----
#pragma unroll
        for (int i = 0; i < 4; ++i) afh[i] = frag_ld(A, arow + 64 + i * 16, q);
        STG(bP, B, 0, kk2);                            // (u+2) B-lo (same slot)
        __builtin_amdgcn_s_barrier();
        asm volatile("s_waitcnt lgkmcnt(0)" ::: "memory");
        __builtin_amdgcn_s_setprio(1);
        MFMA8(4, 2, afh, bfb);
        __builtin_amdgcn_s_setprio(0);
        __builtin_amdgcn_s_barrier();

        // ---- phase 3: (m-hi, n0..1) ----
        STG(bP, B, 1, kk2);                            // (u+2) B-hi (same slot)
        __builtin_amdgcn_s_barrier();
        __builtin_amdgcn_s_setprio(1);
        MFMA8(4, 0, afh, bfa);
        __builtin_amdgcn_s_setprio(0);
        asm volatile("s_waitcnt vmcnt(4)" ::: "memory");  // tile u+1 landed
        __builtin_amdgcn_s_barrier();
    }

    // ------------- epilogue: fused LSE over this block's 64-col chunks
    // C/D layout: col = lane&15 (vocab), row = q*4+r (token)
    const int chunk = by * 4 + wn;
#pragma unroll
    for (int i = 0; i < 8; ++i) {
        float mx[4], sm[4];
#pragma unroll
        for (int r = 0; r < 4; ++r) {
            float m4 = acc[i][0][r];
            m4 = fmaxf(m4, acc[i][1][r]);
            m4 = fmaxf(m4, acc[i][2][r]);
            m4 = fmaxf(m4, acc[i][3][r]);
            mx[r] = m4;
        }
#pragma unroll
        for (int d = 1; d < 16; d <<= 1)
#pragma unroll
            for (int r = 0; r < 4; ++r)
                mx[r] = fmaxf(mx[r], __shfl_xor(mx[r], d, 64));
#pragma unroll
        for (int r = 0; r < 4; ++r) {
            float s = 0.f;
#pragma unroll
            for (int j = 0; j < 4; ++j) s += expf(acc[i][j][r] - mx[r]);
            sm[r] = s;
        }
#pragma unroll
        for (int d = 1; d < 16; d <<= 1)
#pragma unroll
            for (int r = 0; r < 4; ++r)
                sm[r] += __shfl_xor(sm[r], d, 64);

        const int tokenBase = m0 + wm * 128 + i * 16 + q * 4;
        if (c == 0) {
#pragma unroll
            for (int r = 0; r < 4; ++r) {
                pmax[(size_t)(slot * MTOK + tokenBase + r) * NCHUNK + chunk] = mx[r];
                psum[(size_t)(slot * MTOK + tokenBase + r) * NCHUNK + chunk] = sm[r];
            }
        }
        // target-logit capture — LITERAL j index only (runtime index into acc
        // demotes the accumulator to scratch)
#pragma unroll
        for (int r = 0; r < 4; ++r) {
            int lab = y[tokenBase + r];
            int rel = lab - (v0 + wn * 64);
            if (rel >= 0 && rel < 64 && (rel & 15) == c) {
#pragma unroll
                for (int j = 0; j < 4; ++j)
                    if ((rel >> 4) == j)
                        tlog[(size_t)slot * MTOK + tokenBase + r] = acc[i][j][r];
            }
        }
    }
}

// --------------------------------------------- per-token logp (wave/token)
__global__ __launch_bounds__(256) void finalize_kernel(
        const int* __restrict__ y,
        const float* __restrict__ pmax,
        const float* __restrict__ psum,
        const float* __restrict__ tlog,
        float* __restrict__ tokll, int slot_base) {
    const int wv    = threadIdx.x >> 6;
    const int lane  = threadIdx.x & 63;
    const int token = blockIdx.x * 4 + wv;
    const int slot  = slot_base + blockIdx.y;

    const float* pm = &pmax[(size_t)(slot * MTOK + token) * NCHUNK];
    const float* ps = &psum[(size_t)(slot * MTOK + token) * NCHUNK];
    float m = -3.4e38f, s = 0.f;
    for (int c2 = lane; c2 < NCHUNK; c2 += 64) {
        float cm = pm[c2];
        float cs = ps[c2];
        if (cm > m) { s = s * expf(m - cm) + cs; m = cm; }
        else        { s += cs * expf(cm - m); }
    }
#pragma unroll
    for (int d = 1; d < 64; d <<= 1) {
        float om = __shfl_xor(m, d, 64);
        float os = __shfl_xor(s, d, 64);
        if (om > m) { s = s * expf(m - om) + os; m = om; }
        else        { s += os * expf(om - m); }
    }
    if (lane == 0) {
        int lab = y[token];
        float lse = m + logf(s);
        tokll[(size_t)slot * MTOK + token] =
            (lab == IGNORE_INDEX) ? 0.f : (tlog[(size_t)slot * MTOK + token] - lse);
    }
}

// ---------------------------------- fused seq-average + KTO loss, 1 block
__global__ __launch_bounds__(256) void tail_kernel(
        const int* __restrict__ y,
        const float* __restrict__ tokll,
        const int* __restrict__ pref,
        float* __restrict__ out) {
    __shared__ float rs[256];
    __shared__ float rc[256];
    __shared__ float seqavg[8];
    const int tid = threadIdx.x;
    for (int sb = 0; sb < 8; ++sb) {
        const int slot = sb >> 2;
        const int b    = sb & 3;
        float lsum = 0.f, lcnt = 0.f;
        for (int t = tid; t < TSEQ; t += 256) {
            int token = b * TSEQ + t;
            lsum += tokll[(size_t)slot * MTOK + token];
            lcnt += (y[token] != IGNORE_INDEX) ? 1.f : 0.f;
        }
        rs[tid] = lsum; rc[tid] = lcnt;
        __syncthreads();
        for (int s2 = 128; s2 > 0; s2 >>= 1) {
            if (tid < s2) { rs[tid] += rs[tid + s2]; rc[tid] += rc[tid + s2]; }
            __syncthreads();
        }
        if (tid == 0) seqavg[sb] = rs[0] / rc[0];
        __syncthreads();
    }
    if (tid == 0) {
        float acc = 0.f;
        for (int b = 0; b < BATCH; ++b) {
            float lr   = seqavg[b] - seqavg[BATCH + b];
            float mult = pref[b] ? 1.f : -1.f;
            float z    = BETA * lr * mult;
            float sig  = 1.f / (1.f + expf(-z));
            acc += 1.f - sig;
        }
        out[0] = acc * (1.f / (float)BATCH);
    }
}

// ---------------------------------------------------------------- launcher
extern "C" void kernel_launch(void* const* d_in, const int* in_sizes, int n_in,
                              void* d_out, int out_size, void* d_ws, size_t ws_size,
                              hipStream_t stream) {
    const float* x      = (const float*)d_in[0];
    const float* ref_x  = (const float*)d_in[1];
    const int*   y      = (const int*)d_in[2];
    const int*   pref   = (const int*)d_in[3];
    const float* W      = (const float*)d_in[4];
    const float* ref_W  = (const float*)d_in[5];
    float* out = (float*)d_out;
    char*  ws  = (char*)d_ws;

    const size_t WQSZ = (size_t)VOCAB * HDIM;      // 65,536,000 B fp8
    const size_t XQSZ = (size_t)MTOK * HDIM;       //  4,194,304 B fp8
    const size_t PSZ  = (size_t)2 * MTOK * NCHUNK * 4;  // dual-slot pmax/psum

    const size_t need_dual = 2*WQSZ + 2*XQSZ + 2*PSZ + (size_t)4*MTOK*4 + 4096;

    if (ws_size >= need_dual) {
        unsigned char* wq0 = (unsigned char*)(ws);
        unsigned char* wq1 = (unsigned char*)(ws + WQSZ);
        unsigned char* xq0 = (unsigned char*)(ws + 2*WQSZ);
        unsigned char* xq1 = (unsigned char*)(ws + 2*WQSZ + XQSZ);
        float* pmax  = (float*)(ws + 2*WQSZ + 2*XQSZ);
        float* psum  = (float*)(ws + 2*WQSZ + 2*XQSZ + PSZ);
        float* tlog  = (float*)(ws + 2*WQSZ + 2*XQSZ + 2*PSZ);
        float* tokll = (float*)(ws + 2*WQSZ + 2*XQSZ + 2*PSZ + (size_t)2*MTOK*4);

        cvtq_all_kernel<<<2*WCVT_BLK + 2*XCVT_BLK, 256, 0, stream>>>(
            W, ref_W, x, ref_x,
            (unsigned int*)wq0, (unsigned int*)wq1,
            (unsigned int*)xq0, (unsigned int*)xq1);
        gemm_lse_fp8_kernel<<<dim3(MTOK/BM, GRIDY, 2), 512, 0, stream>>>(
            xq0, xq1, wq0, wq1, y, pmax, psum, tlog, 0);
        finalize_kernel<<<dim3(MTOK/4, 2), 256, 0, stream>>>(
            y, pmax, psum, tlog, tokll, 0);
        tail_kernel<<<1, 256, 0, stream>>>(y, tokll, pref, out);
    } else {
        // serial fallback: single W/X buffer reused per model
        unsigned char* wq = (unsigned char*)(ws);
        unsigned char* xq = (unsigned char*)(ws + WQSZ);
        float* pmax  = (float*)(ws + WQSZ + XQSZ);
        float* psum  = (float*)(ws + WQSZ + XQSZ + PSZ);
        float* tlog  = (float*)(ws + WQSZ + XQSZ + 2*PSZ);
        float* tokll = (float*)(ws + WQSZ + XQSZ + 2*PSZ + (size_t)2*MTOK*4);

        for (int model = 0; model < 2; ++model) {
            const float* xin = model ? ref_x : x;
            const float* win = model ? ref_W : W;
            cvtq_one_kernel<<<WCVT_BLK, 256, 0, stream>>>(win, (unsigned int*)wq, WSCALE);
            cvtq_one_kernel<<<XCVT_BLK, 256, 0, stream>>>(xin, (unsigned int*)xq, 1.0f);
            gemm_lse_fp8_kernel<<<dim3(MTOK/BM, GRIDY, 1), 512, 0, stream>>>(
                xq, xq, wq, wq, y, pmax, psum, tlog, model);
            finalize_kernel<<<dim3(MTOK/4, 1), 256, 0, stream>>>(
                y, pmax, psum, tlog, tokll, model);
        }
        tail_kernel<<<1, 256, 0, stream>>>(y, tokll, pref, out);
    }
}